// Round 1
// baseline (193.026 us; speedup 1.0000x reference)
//
#include <hip/hip_runtime.h>
#include <hip/hip_bf16.h>
#include <cstddef>

#define THREADS 256

__device__ __forceinline__ float silu_f(float v)     { return v / (1.f + expf(-v)); }
__device__ __forceinline__ float softplus_f(float v) { return v > 20.f ? v : log1pf(expf(v)); }

// ---------------------------------------------------------------------------
// Shared TN-GEMM core: C[M,N] = A[M,K] @ W[N,K]^T, both row-major (K contig).
// Block tile 64x64, BK=32, 256 threads, 4x4 register tile per thread.
// LDS tiles stored K-major with pad 4 (stride 68 floats -> 16B-aligned rows,
// conflict-light). Bounds checking on N only (M always a multiple of 64 here).
// ---------------------------------------------------------------------------
template<bool BN_BOUND>
__device__ __forceinline__ void gemm_core64(
    const float* __restrict__ A, int lda,
    const float* __restrict__ W, int ldw, int N,
    int kBeg, int kEnd, int m0, int n0,
    float (&acc)[4][4],
    float (&As)[32][68], float (&Ws)[32][68])
{
    const int tid = threadIdx.x;
    const int tn = tid & 15;   // 16 threads across N
    const int tm = tid >> 4;   // 16 threads across M

#pragma unroll
    for (int i = 0; i < 4; i++)
#pragma unroll
        for (int j = 0; j < 4; j++) acc[i][j] = 0.f;

    for (int kt = kBeg; kt < kEnd; kt += 32) {
        // stage A tile (64 rows x 32 k) transposed into As[k][row]
#pragma unroll
        for (int l = 0; l < 2; l++) {
            int idx = tid + l * THREADS;   // float4 index, 512 total
            int row = idx >> 3;            // 0..63
            int kc  = (idx & 7) << 2;      // 0,4,...,28
            float4 v = *reinterpret_cast<const float4*>(
                A + (size_t)(m0 + row) * lda + kt + kc);
            As[kc + 0][row] = v.x; As[kc + 1][row] = v.y;
            As[kc + 2][row] = v.z; As[kc + 3][row] = v.w;
        }
        // stage W tile (64 n-rows x 32 k) transposed into Ws[k][n]
#pragma unroll
        for (int l = 0; l < 2; l++) {
            int idx = tid + l * THREADS;
            int row = idx >> 3;
            int kc  = (idx & 7) << 2;
            float4 v = make_float4(0.f, 0.f, 0.f, 0.f);
            int n = n0 + row;
            if (!BN_BOUND || n < N)
                v = *reinterpret_cast<const float4*>(
                    W + (size_t)n * ldw + kt + kc);
            Ws[kc + 0][row] = v.x; Ws[kc + 1][row] = v.y;
            Ws[kc + 2][row] = v.z; Ws[kc + 3][row] = v.w;
        }
        __syncthreads();

#pragma unroll
        for (int kk = 0; kk < 32; kk++) {
            float4 a4 = *reinterpret_cast<const float4*>(&As[kk][tm << 2]);
            float4 w4 = *reinterpret_cast<const float4*>(&Ws[kk][tn << 2]);
            float a[4] = {a4.x, a4.y, a4.z, a4.w};
            float w[4] = {w4.x, w4.y, w4.z, w4.w};
#pragma unroll
            for (int i = 0; i < 4; i++)
#pragma unroll
                for (int j = 0; j < 4; j++)
                    acc[i][j] = fmaf(a[i], w[j], acc[i][j]);
        }
        __syncthreads();
    }
}

// ---------------------------------------------------------------------------
// Kernel 1: xz = x @ in_proj_w^T  (512 x 2048, K=512), fused conv(+pad) + silu.
// With L=1 the conv reduces to conv_b + conv_w[:,1]*xin (k=0 tap hits the pad).
// n <  1024 -> xin = silu(conv_b[n] + conv_w[n,1]*xz)
// n >= 1024 -> sz  = silu(z)
// ---------------------------------------------------------------------------
__global__ __launch_bounds__(THREADS) void k_inproj(
    const float* __restrict__ x, const float* __restrict__ w,
    const float* __restrict__ conv_w, const float* __restrict__ conv_b,
    float* __restrict__ xin, float* __restrict__ sz)
{
    __shared__ __align__(16) float As[32][68];
    __shared__ __align__(16) float Ws[32][68];
    const int m0 = blockIdx.y * 64, n0 = blockIdx.x * 64;
    const int tn = threadIdx.x & 15, tm = threadIdx.x >> 4;
    float acc[4][4];
    gemm_core64<false>(x, 512, w, 512, 2048, 0, 512, m0, n0, acc, As, Ws);

    const bool is_x_half = (n0 < 1024);   // uniform per block (1024 % 64 == 0)
#pragma unroll
    for (int i = 0; i < 4; i++) {
        int b = m0 + tm * 4 + i;
        int n = n0 + tn * 4;
        float4 o;
        if (is_x_half) {
            float c0 = conv_b[n+0] + conv_w[2*(n+0)+1] * acc[i][0];
            float c1 = conv_b[n+1] + conv_w[2*(n+1)+1] * acc[i][1];
            float c2 = conv_b[n+2] + conv_w[2*(n+2)+1] * acc[i][2];
            float c3 = conv_b[n+3] + conv_w[2*(n+3)+1] * acc[i][3];
            o = make_float4(silu_f(c0), silu_f(c1), silu_f(c2), silu_f(c3));
            *reinterpret_cast<float4*>(xin + (size_t)b * 1024 + n) = o;
        } else {
            o = make_float4(silu_f(acc[i][0]), silu_f(acc[i][1]),
                            silu_f(acc[i][2]), silu_f(acc[i][3]));
            *reinterpret_cast<float4*>(sz + (size_t)b * 1024 + (n - 1024)) = o;
        }
    }
}

// ---------------------------------------------------------------------------
// Kernel 2: x_dbl = xin @ x_proj_w^T  (512 x 288, K=1024), split-K=4,
// atomicAdd into zeroed x_dbl.
// ---------------------------------------------------------------------------
__global__ __launch_bounds__(THREADS) void k_xproj(
    const float* __restrict__ xin, const float* __restrict__ w,
    float* __restrict__ xdbl)
{
    __shared__ __align__(16) float As[32][68];
    __shared__ __align__(16) float Ws[32][68];
    const int m0 = blockIdx.y * 64, n0 = blockIdx.x * 64;
    const int kBeg = blockIdx.z * 256, kEnd = kBeg + 256;
    const int tn = threadIdx.x & 15, tm = threadIdx.x >> 4;
    float acc[4][4];
    gemm_core64<true>(xin, 1024, w, 1024, 288, kBeg, kEnd, m0, n0, acc, As, Ws);

#pragma unroll
    for (int i = 0; i < 4; i++) {
        int b = m0 + tm * 4 + i;
#pragma unroll
        for (int j = 0; j < 4; j++) {
            int n = n0 + tn * 4 + j;
            if (n < 288) atomicAdd(&xdbl[(size_t)b * 288 + n], acc[i][j]);
        }
    }
}

// ---------------------------------------------------------------------------
// Kernel 3: dt = softplus(dt_low @ dt_proj_w^T + dt_proj_b)  (512 x 1024, K=32)
// fused with the collapsed scan:
//   bc[b] = sum_s Bm[b,s]*Cm[b,s]
//   y[b,c] = xin[b,c] * (dt[b,c]*bc[b] + D[c]) * silu(z[b,c])
// ---------------------------------------------------------------------------
__global__ __launch_bounds__(THREADS) void k_dty(
    const float* __restrict__ xdbl, const float* __restrict__ dtw,
    const float* __restrict__ dtb, const float* __restrict__ Dv,
    const float* __restrict__ xin, const float* __restrict__ sz,
    float* __restrict__ y)
{
    __shared__ __align__(16) float As[32][68];
    __shared__ __align__(16) float Ws[32][68];
    __shared__ float bc_s[64];
    __shared__ float bcp[64][4];
    const int m0 = blockIdx.y * 64, n0 = blockIdx.x * 64;
    const int tid = threadIdx.x;
    const int tn = tid & 15, tm = tid >> 4;

    // prologue: bc[b] for this block's 64 rows (4 threads per row)
    {
        int r = tid >> 2, p = tid & 3;
        const float* row = xdbl + (size_t)(m0 + r) * 288;
        float s = 0.f;
#pragma unroll
        for (int t = 0; t < 32; t++)
            s += row[32 + p * 32 + t] * row[160 + p * 32 + t];
        bcp[r][p] = s;
    }
    __syncthreads();
    if (tid < 64) bc_s[tid] = bcp[tid][0] + bcp[tid][1] + bcp[tid][2] + bcp[tid][3];
    __syncthreads();

    float acc[4][4];
    gemm_core64<false>(xdbl, 288, dtw, 32, 1024, 0, 32, m0, n0, acc, As, Ws);

#pragma unroll
    for (int i = 0; i < 4; i++) {
        int b = m0 + tm * 4 + i;
        int n = n0 + tn * 4;
        float bc = bc_s[tm * 4 + i];
        float4 xi = *reinterpret_cast<const float4*>(xin + (size_t)b * 1024 + n);
        float4 zi = *reinterpret_cast<const float4*>(sz  + (size_t)b * 1024 + n);
        float4 o;
        o.x = xi.x * (softplus_f(acc[i][0] + dtb[n+0]) * bc + Dv[n+0]) * zi.x;
        o.y = xi.y * (softplus_f(acc[i][1] + dtb[n+1]) * bc + Dv[n+1]) * zi.y;
        o.z = xi.z * (softplus_f(acc[i][2] + dtb[n+2]) * bc + Dv[n+2]) * zi.z;
        o.w = xi.w * (softplus_f(acc[i][3] + dtb[n+3]) * bc + Dv[n+3]) * zi.w;
        *reinterpret_cast<float4*>(y + (size_t)b * 1024 + n) = o;
    }
}

// ---------------------------------------------------------------------------
// Kernel 4: mout = y @ out_proj_w^T  (512 x 512, K=1024), split-K=4, atomic.
// ---------------------------------------------------------------------------
__global__ __launch_bounds__(THREADS) void k_outproj(
    const float* __restrict__ y, const float* __restrict__ w,
    float* __restrict__ mout)
{
    __shared__ __align__(16) float As[32][68];
    __shared__ __align__(16) float Ws[32][68];
    const int m0 = blockIdx.y * 64, n0 = blockIdx.x * 64;
    const int kBeg = blockIdx.z * 256, kEnd = kBeg + 256;
    const int tn = threadIdx.x & 15, tm = threadIdx.x >> 4;
    float acc[4][4];
    gemm_core64<false>(y, 1024, w, 1024, 512, kBeg, kEnd, m0, n0, acc, As, Ws);

#pragma unroll
    for (int i = 0; i < 4; i++) {
        int b = m0 + tm * 4 + i;
#pragma unroll
        for (int j = 0; j < 4; j++) {
            int n = n0 + tn * 4 + j;
            atomicAdd(&mout[(size_t)b * 512 + n], acc[i][j]);
        }
    }
}

// ---------------------------------------------------------------------------
// Kernel 5: h1 = mout @ fc1_w^T  (512 x 256, K=512), split-K=4, atomic (raw,
// bias + leaky applied in the head kernel after full accumulation).
// ---------------------------------------------------------------------------
__global__ __launch_bounds__(THREADS) void k_fc1(
    const float* __restrict__ mout, const float* __restrict__ w,
    float* __restrict__ h1)
{
    __shared__ __align__(16) float As[32][68];
    __shared__ __align__(16) float Ws[32][68];
    const int m0 = blockIdx.y * 64, n0 = blockIdx.x * 64;
    const int kBeg = blockIdx.z * 128, kEnd = kBeg + 128;
    const int tn = threadIdx.x & 15, tm = threadIdx.x >> 4;
    float acc[4][4];
    gemm_core64<false>(mout, 512, w, 512, 256, kBeg, kEnd, m0, n0, acc, As, Ws);

#pragma unroll
    for (int i = 0; i < 4; i++) {
        int b = m0 + tm * 4 + i;
#pragma unroll
        for (int j = 0; j < 4; j++) {
            int n = n0 + tn * 4 + j;
            atomicAdd(&h1[(size_t)b * 256 + n], acc[i][j]);
        }
    }
}

// ---------------------------------------------------------------------------
// Kernel 6: out[b] = sigmoid(fc5_b + sum_j fc5_w[j] * leaky(h1[b,j]+fc1_b[j]))
// One wave per batch row: 64 lanes x float4 = 256 elements, shuffle-reduce.
// ---------------------------------------------------------------------------
__global__ __launch_bounds__(THREADS) void k_head(
    const float* __restrict__ h1, const float* __restrict__ fc1_b,
    const float* __restrict__ fc5_w, const float* __restrict__ fc5_b,
    float* __restrict__ out)
{
    const int wave = threadIdx.x >> 6;
    const int lane = threadIdx.x & 63;
    const int b = blockIdx.x * 4 + wave;

    float4 h  = *reinterpret_cast<const float4*>(h1 + (size_t)b * 256 + lane * 4);
    float4 bb = *reinterpret_cast<const float4*>(fc1_b + lane * 4);
    float4 w  = *reinterpret_cast<const float4*>(fc5_w + lane * 4);

    float v0 = h.x + bb.x, v1 = h.y + bb.y, v2 = h.z + bb.z, v3 = h.w + bb.w;
    v0 = v0 >= 0.f ? v0 : 0.1f * v0;
    v1 = v1 >= 0.f ? v1 : 0.1f * v1;
    v2 = v2 >= 0.f ? v2 : 0.1f * v2;
    v3 = v3 >= 0.f ? v3 : 0.1f * v3;
    float s = v0 * w.x + v1 * w.y + v2 * w.z + v3 * w.w;

#pragma unroll
    for (int off = 32; off > 0; off >>= 1) s += __shfl_xor(s, off, 64);

    if (lane == 0) out[b] = 1.f / (1.f + expf(-(s + fc5_b[0])));
}

// ---------------------------------------------------------------------------
extern "C" void kernel_launch(void* const* d_in, const int* in_sizes, int n_in,
                              void* d_out, int out_size, void* d_ws, size_t ws_size,
                              hipStream_t stream)
{
    const float* x    = (const float*)d_in[0];
    const float* wip  = (const float*)d_in[1];
    const float* cw   = (const float*)d_in[2];
    const float* cb   = (const float*)d_in[3];
    const float* wxp  = (const float*)d_in[4];
    const float* wdt  = (const float*)d_in[5];
    const float* bdt  = (const float*)d_in[6];
    // d_in[7] = A_log: unused — h0 == 0 so dA never contributes at L==1.
    const float* Dv   = (const float*)d_in[8];
    const float* wout = (const float*)d_in[9];
    const float* wfc1 = (const float*)d_in[10];
    const float* bfc1 = (const float*)d_in[11];
    const float* wfc5 = (const float*)d_in[12];
    const float* bfc5 = (const float*)d_in[13];
    float* out = (float*)d_out;

    float* ws   = (float*)d_ws;
    float* xin  = ws;                    // 512*1024
    float* sz   = xin  + 512 * 1024;     // 512*1024
    float* xdbl = sz   + 512 * 1024;     // 512*288
    float* y    = xdbl + 512 * 288;      // 512*1024
    float* mout = y    + 512 * 1024;     // 512*512
    float* h1   = mout + 512 * 512;      // 512*256   (total ~8.5 MB)

    // zero split-K accumulation buffers (ws is poisoned 0xAA before each call)
    hipMemsetAsync(xdbl, 0, 512 * 288 * sizeof(float), stream);
    hipMemsetAsync(mout, 0, 512 * 512 * sizeof(float), stream);
    hipMemsetAsync(h1,   0, 512 * 256 * sizeof(float), stream);

    k_inproj <<<dim3(32, 8),    THREADS, 0, stream>>>(x, wip, cw, cb, xin, sz);
    k_xproj  <<<dim3(5, 8, 4),  THREADS, 0, stream>>>(xin, wxp, xdbl);
    k_dty    <<<dim3(16, 8),    THREADS, 0, stream>>>(xdbl, wdt, bdt, Dv, xin, sz, y);
    k_outproj<<<dim3(8, 8, 4),  THREADS, 0, stream>>>(y, wout, mout);
    k_fc1    <<<dim3(4, 8, 4),  THREADS, 0, stream>>>(mout, wfc1, h1);
    k_head   <<<dim3(128),      THREADS, 0, stream>>>(h1, bfc1, wfc5, bfc5, out);
}